// Round 5
// baseline (515.851 us; speedup 1.0000x reference)
//
#include <hip/hip_runtime.h>
#include <hip/hip_bf16.h>
#include <math.h>

// ---------------------------------------------------------------------------
// Autoformer encoder layer, MI355X (gfx950).
// B=4, L=4096, D=512, H=8, dk=64, F=2048, MA=25, top_k=8.
// All GEMMs in fp16 MFMA (16x16x32_f16), fp32 accumulate.
// ---------------------------------------------------------------------------

typedef _Float16 half8_t __attribute__((ext_vector_type(8)));
typedef _Float16 half4_t __attribute__((ext_vector_type(4)));
typedef float    f32x4_t __attribute__((ext_vector_type(4)));

__device__ __forceinline__ void gl_lds16(const _Float16* src, _Float16* dst) {
  __builtin_amdgcn_global_load_lds(
      (const __attribute__((address_space(1))) unsigned int*)(const void*)src,
      (__attribute__((address_space(3))) unsigned int*)(void*)dst, 16, 0, 0);
}

// ---------------------------------------------------------------------------
// Generic fp16 GEMM:  out[M,N] = A[M,K] @ Bt[N,K]^T + bias, optional GELU.
// 128x128 tile, BK=64, 256 threads (4 waves, 2x2), XOR-swizzled LDS.
// SWAPPED-OPERAND epilogue: mfma(bf, af) puts N on the reg axis -> each
// thread's 4 acc regs are 4 consecutive N-cols -> f32x4/half4 stores.
// Bias: 3 segment pointers, segment = n0 >> segShift (for fused QKV).
// ---------------------------------------------------------------------------
template<bool OUT16, bool DOGELU>
__global__ __launch_bounds__(256) void gemm_f16k(
    const _Float16* __restrict__ A, const _Float16* __restrict__ Bt,
    const float* __restrict__ bs0, const float* __restrict__ bs1,
    const float* __restrict__ bs2, int segShift,
    void* __restrict__ outp, int M, int N, int K)
{
  __shared__ _Float16 As[128 * 64];
  __shared__ _Float16 Bs[128 * 64];
  const int tid = threadIdx.x, lane = tid & 63, w = tid >> 6;
  const int wr = w >> 1, wc = w & 1;
  const int m0 = blockIdx.x * 128, n0 = blockIdx.y * 128;

  f32x4_t acc[4][4];
  #pragma unroll
  for (int i = 0; i < 4; ++i)
    #pragma unroll
    for (int j = 0; j < 4; ++j) acc[i][j] = (f32x4_t){0.f, 0.f, 0.f, 0.f};

  const _Float16* Ab = A + (size_t)m0 * K;
  const _Float16* Bb = Bt + (size_t)n0 * K;

  for (int k0 = 0; k0 < K; k0 += 64) {
    #pragma unroll
    for (int q = 0; q < 4; ++q) {
      int off = ((w << 2) + q) << 10;            // byte offset of wave-issue
      int row = (off >> 7) + (lane >> 3);
      int sl  = (lane & 7) ^ (row & 7);          // logical k-slot for this phys slot
      gl_lds16(Ab + (size_t)row * K + k0 + (sl << 3), As + (off >> 1));
    }
    #pragma unroll
    for (int q = 0; q < 4; ++q) {
      int off = ((w << 2) + q) << 10;
      int row = (off >> 7) + (lane >> 3);
      int sl  = (lane & 7) ^ (row & 7);
      gl_lds16(Bb + (size_t)row * K + k0 + (sl << 3), Bs + (off >> 1));
    }
    __syncthreads();

    #pragma unroll
    for (int kk = 0; kk < 2; ++kk) {
      half8_t af[4], bf[4];
      #pragma unroll
      for (int mi = 0; mi < 4; ++mi) {
        int row = wr * 64 + mi * 16 + (lane & 15);
        int sl  = ((kk << 2) + (lane >> 4)) ^ (row & 7);
        af[mi] = *(const half8_t*)(As + row * 64 + (sl << 3));
      }
      #pragma unroll
      for (int ni = 0; ni < 4; ++ni) {
        int row = wc * 64 + ni * 16 + (lane & 15);
        int sl  = ((kk << 2) + (lane >> 4)) ^ (row & 7);
        bf[ni] = *(const half8_t*)(Bs + row * 64 + (sl << 3));
      }
      #pragma unroll
      for (int mi = 0; mi < 4; ++mi)
        #pragma unroll
        for (int ni = 0; ni < 4; ++ni)
          acc[mi][ni] = __builtin_amdgcn_mfma_f32_16x16x32_f16(
              bf[ni], af[mi], acc[mi][ni], 0, 0, 0);   // swapped: N on reg axis
    }
    __syncthreads();
  }

  int seg = n0 >> segShift; if (seg > 2) seg = 2;
  const float* bias = seg == 0 ? bs0 : (seg == 1 ? bs1 : bs2);
  const unsigned bmask = (segShift >= 31) ? 0xffffffffu : ((1u << segShift) - 1u);

  #pragma unroll
  for (int ni = 0; ni < 4; ++ni) {
    int n = n0 + wc * 64 + ni * 16 + ((lane >> 4) << 2);
    f32x4_t b4 = *(const f32x4_t*)(bias + (n & bmask));
    #pragma unroll
    for (int mi = 0; mi < 4; ++mi) {
      int m = m0 + wr * 64 + mi * 16 + (lane & 15);
      f32x4_t v = acc[mi][ni] + b4;
      if (DOGELU) {
        #pragma unroll
        for (int r = 0; r < 4; ++r)
          v[r] = 0.5f * v[r] * (1.f + erff(v[r] * 0.70710678118654752f));
      }
      if (OUT16) {
        half4_t o;
        o[0] = (_Float16)v[0]; o[1] = (_Float16)v[1];
        o[2] = (_Float16)v[2]; o[3] = (_Float16)v[3];
        *(half4_t*)((_Float16*)outp + (size_t)m * N + n) = o;
      } else {
        *(f32x4_t*)((float*)outp + (size_t)m * N + n) = v;
      }
    }
  }
}

// ---------------------------------------------------------------------------
// Autocorrelation v5: block owns (b, h, tau-window [64T, 64T+64)).
// One 64x64x4096 band GEMM accumulated in registers across 64 J-tiles.
// All addressing hoisted out of the loop; J-loop unrolled x2 with statically
// named double buffers (LDS offsets become immediates). Q/K read from the
// fused QKV buffer (stride 1536; K at +512). Diagonal extraction once.
// ---------------------------------------------------------------------------
__global__ __launch_bounds__(256) void corr_gram5(
    const _Float16* __restrict__ QKV,
    float* __restrict__ corrP, float* __restrict__ corrN)
{
  __shared__ __attribute__((aligned(16))) char smem[34816];
  _Float16* Qs0 = (_Float16*)smem;            // [4096] halfs
  _Float16* Qs1 = Qs0 + 4096;
  _Float16* Ks0 = Qs0 + 8192;
  _Float16* Ks1 = Qs0 + 12288;
  float*    Gd  = (float*)smem;               // [128][68] after loop

  const int tid = threadIdx.x, lane = tid & 63, w = tid >> 6;
  const int p  = blockIdx.x;
  const int lg = ((p & 7) << 8) + (p >> 3);   // XCD-chunked swizzle
  const int T = lg & 63, h = (lg >> 6) & 7, b = lg >> 9;
  const int qr = w >> 1, qc = w & 1;

  // ---- hoisted per-thread staging offsets (2 issues each for Q and K)
  size_t qoff[2], koff[2]; int loff[2];
  #pragma unroll
  for (int q_ = 0; q_ < 2; ++q_) {
    int off_ = ((w << 1) + q_) << 10;
    int row_ = (off_ >> 7) + (lane >> 3);
    int sl_  = (lane & 7) ^ (row_ & 7);
    loff[q_] = off_ >> 1;
    qoff[q_] = (size_t)row_ * 1536 + (sl_ << 3) + h * 64;
    koff[q_] = qoff[q_] + 512;
  }
  const size_t bbase = (size_t)b * 4096 * 1536;

  // ---- hoisted frag LDS offsets (halfs)
  int aoff[2][2], boff[2][2];
  #pragma unroll
  for (int mi = 0; mi < 2; ++mi) {
    int row = (qr << 5) + (mi << 4) + (lane & 15);
    #pragma unroll
    for (int kk = 0; kk < 2; ++kk) {
      int sl = ((kk << 2) + (lane >> 4)) ^ (row & 7);
      aoff[mi][kk] = row * 64 + (sl << 3);
    }
  }
  #pragma unroll
  for (int ni = 0; ni < 2; ++ni) {
    int row = (qc << 5) + (ni << 4) + (lane & 15);
    #pragma unroll
    for (int kk = 0; kk < 2; ++kk) {
      int sl = ((kk << 2) + (lane >> 4)) ^ (row & 7);
      boff[ni][kk] = row * 64 + (sl << 3);
    }
  }

  f32x4_t acc[2][2];
  #pragma unroll
  for (int i = 0; i < 2; ++i)
    #pragma unroll
    for (int j = 0; j < 2; ++j) acc[i][j] = (f32x4_t){0.f, 0.f, 0.f, 0.f};

  auto stage = [&](_Float16* Qd, _Float16* Kd, int qt, int kt) {
    const size_t qb = bbase + (size_t)qt * 98304;   // 64*1536
    const size_t kb = bbase + (size_t)kt * 98304;
    #pragma unroll
    for (int q_ = 0; q_ < 2; ++q_) {
      gl_lds16(QKV + qb + qoff[q_], Qd + loff[q_]);
      gl_lds16(QKV + kb + koff[q_], Kd + loff[q_]);
    }
  };
  auto compute = [&](const _Float16* Qb, const _Float16* Kb) {
    half8_t a[2][2], bfr[2][2];
    #pragma unroll
    for (int mi = 0; mi < 2; ++mi)
      #pragma unroll
      for (int kk = 0; kk < 2; ++kk)
        a[mi][kk] = *(const half8_t*)(Qb + aoff[mi][kk]);
    #pragma unroll
    for (int ni = 0; ni < 2; ++ni)
      #pragma unroll
      for (int kk = 0; kk < 2; ++kk)
        bfr[ni][kk] = *(const half8_t*)(Kb + boff[ni][kk]);
    #pragma unroll
    for (int mi = 0; mi < 2; ++mi)
      #pragma unroll
      for (int ni = 0; ni < 2; ++ni) {
        acc[mi][ni] = __builtin_amdgcn_mfma_f32_16x16x32_f16(
            a[mi][0], bfr[ni][0], acc[mi][ni], 0, 0, 0);
        acc[mi][ni] = __builtin_amdgcn_mfma_f32_16x16x32_f16(
            a[mi][1], bfr[ni][1], acc[mi][ni], 0, 0, 0);
      }
  };

  stage(Qs0, Ks0, T, 0);
  __syncthreads();
  for (int J = 0; J < 64; J += 2) {
    stage(Qs1, Ks1, (T + J + 1) & 63, J + 1);
    compute(Qs0, Ks0);
    __syncthreads();                     // reads done + Qs1/Ks1 landed
    if (J + 2 < 64) stage(Qs0, Ks0, (T + J + 2) & 63, J + 2);
    compute(Qs1, Ks1);
    __syncthreads();
  }

  // ---- once-per-block diagonal extraction (Gd aliases stage buffers)
  for (int i = tid; i < 128 * 68; i += 256) Gd[i] = 0.f;
  __syncthreads();
  #pragma unroll
  for (int mi = 0; mi < 2; ++mi)
    #pragma unroll
    for (int ni = 0; ni < 2; ++ni)
      #pragma unroll
      for (int r = 0; r < 4; ++r) {
        int row = (qr << 5) + (mi << 4) + ((lane >> 4) << 2) + r;
        int col = (qc << 5) + (ni << 4) + (lane & 15);
        Gd[(row - col + 64) * 68 + col] = acc[mi][ni][r];
      }
  __syncthreads();

  float s;
  {
    const float* gp = &Gd[(tid >> 1) * 68 + ((tid & 1) << 5)];
    f32x4_t x0 = *(const f32x4_t*)gp        + *(const f32x4_t*)(gp + 4);
    f32x4_t x1 = *(const f32x4_t*)(gp + 8)  + *(const f32x4_t*)(gp + 12);
    f32x4_t x2 = *(const f32x4_t*)(gp + 16) + *(const f32x4_t*)(gp + 20);
    f32x4_t x3 = *(const f32x4_t*)(gp + 24) + *(const f32x4_t*)(gp + 28);
    x0 += x1; x2 += x3; x0 += x2;
    s = x0[0] + x0[1] + x0[2] + x0[3];
  }
  s += __shfl_xor(s, 1);
  if ((tid & 1) == 0) {
    const size_t bh = (size_t)(b * 8 + h) << 12;
    int v = tid >> 1;
    if (v == 0) {
      corrN[bh + (T << 6)] = 0.f;          // tau==0 mod 64: no negative part
    } else {
      int d = v - 64;
      int tau = ((T << 6) + d) & 4095;
      if (d >= 0) corrP[bh + tau] = s;
      else        corrN[bh + tau] = s;
    }
  }
}

// ---------------------------------------------------------------------------
// Top-8 + softmax per (b,h). corr = corrP + corrN. Lowest-index tie-break.
// ---------------------------------------------------------------------------
__global__ __launch_bounds__(256) void topk_softmax(
    const float* __restrict__ corrP, const float* __restrict__ corrN,
    float* __restrict__ tw, int* __restrict__ ti)
{
  __shared__ float vals[4096];
  __shared__ float wvv[4]; __shared__ int wii[4];
  __shared__ float rv[8]; __shared__ int ri[8];
  const int tid = threadIdx.x;
  const int bh = blockIdx.x;
  const float* cp = corrP + (size_t)bh * 4096;
  const float* cn = corrN + (size_t)bh * 4096;
  for (int i = tid; i < 4096; i += 256) vals[i] = cp[i] + cn[i];
  __syncthreads();

  for (int it = 0; it < 8; ++it) {
    float bv = -3.4e38f; int bi = 1 << 30;
    for (int i = tid; i < 4096; i += 256) {
      float v = vals[i];
      if (v > bv) { bv = v; bi = i; }
    }
    #pragma unroll
    for (int o = 32; o > 0; o >>= 1) {
      float ov = __shfl_down(bv, o);
      int   oi = __shfl_down(bi, o);
      if (ov > bv || (ov == bv && oi < bi)) { bv = ov; bi = oi; }
    }
    if ((tid & 63) == 0) { wvv[tid >> 6] = bv; wii[tid >> 6] = bi; }
    __syncthreads();
    if (tid == 0) {
      for (int k = 1; k < 4; ++k)
        if (wvv[k] > bv || (wvv[k] == bv && wii[k] < bi)) { bv = wvv[k]; bi = wii[k]; }
      rv[it] = bv; ri[it] = bi; vals[bi] = -3.4e38f;
    }
    __syncthreads();
  }

  if (tid == 0) {
    float m = rv[0] * (1.f / 64.f);          // corr_mean = corr/dk; rv[0] is max
    float e[8]; float s = 0.f;
    for (int k = 0; k < 8; ++k) { e[k] = expf(rv[k] * (1.f / 64.f) - m); s += e[k]; }
    float inv = 1.f / s;
    for (int k = 0; k < 8; ++k) { tw[bh * 8 + k] = e[k] * inv; ti[bh * 8 + k] = ri[k]; }
  }
}

// ---------------------------------------------------------------------------
// out[b,l,h*64+d] = sum_k tw[k] * V[b,(l+ti[k])%L, h*64+d]; V inside QKV
// (stride 1536, col offset 1024). Output fp16 [16384][512].
// ---------------------------------------------------------------------------
__global__ __launch_bounds__(256) void gather_attn(
    const _Float16* __restrict__ QKV, const float* __restrict__ tw,
    const int* __restrict__ ti, _Float16* __restrict__ outp)
{
  const int tid = threadIdx.x;
  const int d4 = tid & 127;
  const int r  = (blockIdx.x << 1) + (tid >> 7);
  const int b  = r >> 12, l = r & 4095;
  const int h  = d4 >> 4;
  const float* w8 = tw + (((b << 3) + h) << 3);
  const int*   i8 = ti + (((b << 3) + h) << 3);
  f32x4_t acc = (f32x4_t){0.f, 0.f, 0.f, 0.f};
  #pragma unroll
  for (int k = 0; k < 8; ++k) {
    int ls = (l + i8[k]) & 4095;
    half4_t v = *(const half4_t*)(QKV + ((size_t)((b << 12) + ls)) * 1536 + 1024 + (d4 << 2));
    float wk = w8[k];
    acc[0] += (float)v[0] * wk; acc[1] += (float)v[1] * wk;
    acc[2] += (float)v[2] * wk; acc[3] += (float)v[3] * wk;
  }
  half4_t o;
  o[0] = (_Float16)acc[0]; o[1] = (_Float16)acc[1];
  o[2] = (_Float16)acc[2]; o[3] = (_Float16)acc[3];
  *(half4_t*)(outp + ((size_t)r << 9) + (d4 << 2)) = o;
}

// ---------------------------------------------------------------------------
// y = LayerNorm(xa + xb) * g + be   (one wave per 512-wide row)
// ---------------------------------------------------------------------------
__global__ __launch_bounds__(256) void ln_add(
    const float* __restrict__ xa, const float* __restrict__ xb,
    const float* __restrict__ g, const float* __restrict__ be,
    float* __restrict__ y)
{
  const int lane = threadIdx.x & 63;
  const int row  = (blockIdx.x << 2) + (threadIdx.x >> 6);
  const size_t base = (size_t)row << 9;
  const float* ar = xa + base + (lane << 3);
  const float* br = xb + base + (lane << 3);
  f32x4_t a0 = *(const f32x4_t*)ar,       a1 = *(const f32x4_t*)(ar + 4);
  f32x4_t b0 = *(const f32x4_t*)br,       b1 = *(const f32x4_t*)(br + 4);
  f32x4_t v0 = a0 + b0, v1 = a1 + b1;
  float s  = v0[0] + v0[1] + v0[2] + v0[3] + v1[0] + v1[1] + v1[2] + v1[3];
  float s2 = v0[0]*v0[0] + v0[1]*v0[1] + v0[2]*v0[2] + v0[3]*v0[3]
           + v1[0]*v1[0] + v1[1]*v1[1] + v1[2]*v1[2] + v1[3]*v1[3];
  #pragma unroll
  for (int o = 1; o < 64; o <<= 1) { s += __shfl_xor(s, o); s2 += __shfl_xor(s2, o); }
  float mu  = s * (1.f / 512.f);
  float var = s2 * (1.f / 512.f) - mu * mu;
  float rs  = rsqrtf(var + 1e-5f);
  const float* gr  = g  + (lane << 3);
  const float* ber = be + (lane << 3);
  f32x4_t g0 = *(const f32x4_t*)gr,  g1v = *(const f32x4_t*)(gr + 4);
  f32x4_t e0 = *(const f32x4_t*)ber, e1  = *(const f32x4_t*)(ber + 4);
  f32x4_t o0, o1;
  #pragma unroll
  for (int i = 0; i < 4; ++i) {
    o0[i] = (v0[i] - mu) * rs * g0[i]  + e0[i];
    o1[i] = (v1[i] - mu) * rs * g1v[i] + e1[i];
  }
  float* yr = y + base + (lane << 3);
  *(f32x4_t*)yr = o0; *(f32x4_t*)(yr + 4) = o1;
}

// ---------------------------------------------------------------------------
// Series decomposition: moving average window 25, edge-replicated.
// mode 1: write seasonal fp32 + fp16, trend fp32
// mode 2: write seasonal fp32 (d_out), trendOut += trend (trend1+trend2)
// ---------------------------------------------------------------------------
__global__ __launch_bounds__(256) void movavg_decomp(
    const float* __restrict__ y, float* __restrict__ seasF,
    _Float16* __restrict__ seasH, float* __restrict__ trendOut, int mode)
{
  __shared__ float T[152 * 64];
  const int lt = blockIdx.x, dc = blockIdx.y, b = blockIdx.z;
  const int l0 = lt << 7, d0 = dc << 6;
  const int tid = threadIdx.x;
  for (int idx = tid; idx < 152 * 16; idx += 256) {
    int rr = idx >> 4, c4 = idx & 15;
    int ls = l0 - 12 + rr;
    ls = ls < 0 ? 0 : (ls > 4095 ? 4095 : ls);
    *(f32x4_t*)&T[rr * 64 + (c4 << 2)] =
        *(const f32x4_t*)(y + (((size_t)(b << 12) + ls) << 9) + d0 + (c4 << 2));
  }
  __syncthreads();
  for (int idx = tid; idx < 128 * 16; idx += 256) {
    int rr = idx >> 4, c4 = idx & 15;
    f32x4_t s = (f32x4_t){0.f, 0.f, 0.f, 0.f};
    #pragma unroll
    for (int j = 0; j < 25; ++j) s += *(const f32x4_t*)&T[(rr + j) * 64 + (c4 << 2)];
    f32x4_t trend = s * (1.f / 25.f);
    f32x4_t ctr   = *(const f32x4_t*)&T[(rr + 12) * 64 + (c4 << 2)];
    f32x4_t seas  = ctr - trend;
    size_t gp = (((size_t)(b << 12) + l0 + rr) << 9) + d0 + (c4 << 2);
    if (mode == 1) {
      *(f32x4_t*)(seasF + gp) = seas;
      half4_t sh;
      sh[0] = (_Float16)seas[0]; sh[1] = (_Float16)seas[1];
      sh[2] = (_Float16)seas[2]; sh[3] = (_Float16)seas[3];
      *(half4_t*)(seasH + gp) = sh;
      *(f32x4_t*)(trendOut + gp) = trend;
    } else {
      *(f32x4_t*)(seasF + gp) = seas;
      f32x4_t t1 = *(const f32x4_t*)(trendOut + gp);
      t1 += trend;
      *(f32x4_t*)(trendOut + gp) = t1;
    }
  }
}

// ---------------------------------------------------------------------------
// Weight prep, all 6 in one dispatch. Q/K/V transposed into ONE fused
// [1536][512] fp16 buffer (row = global output col); Wo/W1/W2 separate.
// ---------------------------------------------------------------------------
__global__ __launch_bounds__(256) void transpose_all(
    const float* __restrict__ Wq, const float* __restrict__ Wk,
    const float* __restrict__ Wv, const float* __restrict__ Wo,
    const float* __restrict__ W1, const float* __restrict__ W2,
    _Float16* __restrict__ WQKVT, _Float16* __restrict__ WOT,
    _Float16* __restrict__ W1T, _Float16* __restrict__ W2T)
{
  const int id = blockIdx.x;
  const float* src; _Float16* dst; int Kd, Nd, kb, nb, nbase;
  if (id < 1024) {
    int wsel = id >> 8, r = id & 255;
    kb = (r & 15) << 5; nb = (r >> 4) << 5; Kd = 512; Nd = 512;
    src = wsel == 0 ? Wq : wsel == 1 ? Wk : wsel == 2 ? Wv : Wo;
    if (wsel < 3) { dst = WQKVT; nbase = (wsel << 9) + nb; }
    else          { dst = WOT;   nbase = nb; }
  } else if (id < 2048) {
    int r = id - 1024;
    kb = (r & 15) << 5; nb = (r >> 4) << 5; Kd = 512; Nd = 2048;
    src = W1; dst = W1T; nbase = nb;
  } else {
    int r = id - 2048;
    kb = (r & 63) << 5; nb = (r >> 6) << 5; Kd = 2048; Nd = 512;
    src = W2; dst = W2T; nbase = nb;
  }
  __shared__ float t[32][33];
  const int tx = threadIdx.x & 31, ty = threadIdx.x >> 5;
  #pragma unroll
  for (int r0 = 0; r0 < 32; r0 += 8)
    t[ty + r0][tx] = src[(size_t)(kb + ty + r0) * Nd + nb + tx];
  __syncthreads();
  #pragma unroll
  for (int r0 = 0; r0 < 32; r0 += 8)
    dst[(size_t)(nbase + ty + r0) * Kd + kb + tx] = (_Float16)t[tx][ty + r0];
}

__global__ __launch_bounds__(256) void f32_to_f16v(
    const float* __restrict__ src, _Float16* __restrict__ dst, int n4)
{
  int i = blockIdx.x * 256 + threadIdx.x;
  if (i >= n4) return;
  f32x4_t v = *(const f32x4_t*)(src + ((size_t)i << 2));
  half4_t o;
  o[0] = (_Float16)v[0]; o[1] = (_Float16)v[1];
  o[2] = (_Float16)v[2]; o[3] = (_Float16)v[3];
  *(half4_t*)(dst + ((size_t)i << 2)) = o;
}

// ---------------------------------------------------------------------------
extern "C" void kernel_launch(void* const* d_in, const int* in_sizes, int n_in,
                              void* d_out, int out_size, void* d_ws, size_t ws_size,
                              hipStream_t stream)
{
  const float* x   = (const float*)d_in[0];
  const float* Wq  = (const float*)d_in[1];
  const float* bq  = (const float*)d_in[2];
  const float* Wk  = (const float*)d_in[3];
  const float* bk  = (const float*)d_in[4];
  const float* Wv  = (const float*)d_in[5];
  const float* bv  = (const float*)d_in[6];
  const float* Wo  = (const float*)d_in[7];
  const float* bo  = (const float*)d_in[8];
  const float* W1  = (const float*)d_in[9];
  const float* b1  = (const float*)d_in[10];
  const float* W2  = (const float*)d_in[11];
  const float* b2  = (const float*)d_in[12];
  const float* g1  = (const float*)d_in[13];
  const float* be1 = (const float*)d_in[14];
  const float* g2  = (const float*)d_in[15];
  const float* be2 = (const float*)d_in[16];

  char* ws = (char*)d_ws;
  constexpr size_t ME = 16384ull * 512ull;                 // 8,388,608 elems
  // static regions
  constexpr size_t OFF_X16   = 0;                          // 16.8 MB fp16
  constexpr size_t OFF_WQKVT = OFF_X16 + 2 * ME;           // 1536x512 fp16
  constexpr size_t OFF_WOT   = OFF_WQKVT + 1536 * 512 * 2;
  constexpr size_t OFF_W1T   = OFF_WOT + 512 * 512 * 2;
  constexpr size_t OFF_W2T   = OFF_W1T + 2048 * 512 * 2;
  constexpr size_t OFF_QKV16 = OFF_W2T + 2048 * 512 * 2;   // 50.3 MB fp16 [16384][1536]
  constexpr size_t OFF_ATTN  = OFF_QKV16 + 6 * ME;         // 33.5 MB fp32
  constexpr size_t OFF_S132  = OFF_ATTN + 4 * ME;          // 33.5 MB fp32
  constexpr size_t OFF_CORRP = OFF_S132 + 4 * ME;          // 0.5 MB
  constexpr size_t OFF_TW    = OFF_CORRP + 32 * 4096 * 4;
  constexpr size_t OFF_TI    = OFF_TW + 1024;
  // aliases (lifetime-disjoint reuse)
  constexpr size_t OFF_AIN16 = OFF_X16;    // gather out (X16 dead after QKV)
  constexpr size_t OFF_S116  = OFF_X16;    // seasonal1 fp16 (AIN16 dead after O-proj)
  constexpr size_t OFF_Y1    = OFF_QKV16;  // QKV dead after gather
  constexpr size_t OFF_H16   = OFF_QKV16;  // 67 MB; Y1 dead after movavg1 (spans into dead CORR/ATTN? no: 23.0M+67M=90.2M < OFF_ATTN? fits: 6*ME=50.3M + needs 16.7M more -> overlaps ATTN start; ATTN dead after ln1, OK)
  constexpr size_t OFF_Y2    = OFF_QKV16;  // H16 dead after FFN2
  constexpr size_t OFF_CORRN = OFF_ATTN;   // ATTN written only after topk

  _Float16* X16   = (_Float16*)(ws + OFF_X16);
  _Float16* WQKVT = (_Float16*)(ws + OFF_WQKVT);
  _Float16* WOT   = (_Float16*)(ws + OFF_WOT);
  _Float16* W1T   = (_Float16*)(ws + OFF_W1T);
  _Float16* W2T   = (_Float16*)(ws + OFF_W2T);
  _Float16* QKV16 = (_Float16*)(ws + OFF_QKV16);
  float*    ATTN  = (float*)(ws + OFF_ATTN);
  float*    S132  = (float*)(ws + OFF_S132);
  float*    CORRP = (float*)(ws + OFF_CORRP);
  float*    CORRN = (float*)(ws + OFF_CORRN);
  float*    TW    = (float*)(ws + OFF_TW);
  int*      TI    = (int*)(ws + OFF_TI);
  _Float16* AIN16 = (_Float16*)(ws + OFF_AIN16);
  _Float16* S116  = (_Float16*)(ws + OFF_S116);
  _Float16* H16   = (_Float16*)(ws + OFF_H16);
  float*    Y1    = (float*)(ws + OFF_Y1);
  float*    Y2    = (float*)(ws + OFF_Y2);

  float* OUT_SEAS  = (float*)d_out;            // seasonal2
  float* OUT_TREND = (float*)d_out + ME;       // trend1 + trend2
  float* FF        = OUT_SEAS;                 // FFN2 scratch; overwritten by movavg2

  // --- prep ---
  f32_to_f16v<<<8192, 256, 0, stream>>>(x, X16, (int)(ME / 4));
  transpose_all<<<3072, 256, 0, stream>>>(Wq, Wk, Wv, Wo, W1, W2,
                                          WQKVT, WOT, W1T, W2T);

  // --- fused QKV projection: [16384,1536] = X16 @ WQKVT^T ---
  gemm_f16k<true, false><<<dim3(128, 12), 256, 0, stream>>>(
      X16, WQKVT, bq, bk, bv, 9, QKV16, 16384, 1536, 512);

  // --- autocorrelation ---
  corr_gram5<<<2048, 256, 0, stream>>>(QKV16, CORRP, CORRN);
  topk_softmax<<<32, 256, 0, stream>>>(CORRP, CORRN, TW, TI);
  gather_attn<<<8192, 256, 0, stream>>>(QKV16, TW, TI, AIN16);
  gemm_f16k<false, false><<<dim3(128, 4), 256, 0, stream>>>(
      AIN16, WOT, bo, bo, bo, 31, ATTN, 16384, 512, 512);

  // --- LN1 + decomp1 ---
  ln_add<<<4096, 256, 0, stream>>>(x, ATTN, g1, be1, Y1);
  movavg_decomp<<<dim3(32, 8, 4), 256, 0, stream>>>(Y1, S132, S116, OUT_TREND, 1);

  // --- FFN ---
  gemm_f16k<true, true ><<<dim3(128, 16), 256, 0, stream>>>(
      S116, W1T, b1, b1, b1, 31, H16, 16384, 2048, 512);
  gemm_f16k<false, false><<<dim3(128, 4), 256, 0, stream>>>(
      H16, W2T, b2, b2, b2, 31, FF, 16384, 512, 2048);

  // --- LN2 + decomp2 ---
  ln_add<<<4096, 256, 0, stream>>>(S132, FF, g2, be2, Y2);
  movavg_decomp<<<dim3(32, 8, 4), 256, 0, stream>>>(Y2, OUT_SEAS, (_Float16*)nullptr, OUT_TREND, 2);
}